// Round 1
// baseline (7908.797 us; speedup 1.0000x reference)
//
#include <hip/hip_runtime.h>
#include <cmath>

#define S_LEN 32
#define E_DIM 128
#define H_DIM 256
#define V_DIM 512
#define K_TOT (E_DIM + H_DIM)  // 384

__device__ __forceinline__ float sigf(float x) { return 1.0f / (1.0f + expf(-x)); }

// ---------------------------------------------------------------------------
// Fused LSTM step: Z = [emb[idx] | h_in] @ [Wih | Whh]^T + bih + bhh,
// then i,f,g,o split + cell update, writing h_out and c in the epilogue.
// BM=32 rows x (4 gates x BN=64 hidden cols) per block; grid (B/32, H/64)=256 blocks.
// ---------------------------------------------------------------------------
__launch_bounds__(256)
__global__ void lstm_step_kernel(const float* __restrict__ emb,      // [V, E]
                                 const int* __restrict__ idx_src,    // token index source
                                 int idx_stride, int idx_off,        // idx = idx_src[b*stride + off]
                                 const float* __restrict__ Wih,      // [4H, E]
                                 const float* __restrict__ Whh,      // [4H, H]
                                 const float* __restrict__ bih,      // [4H]
                                 const float* __restrict__ bhh,      // [4H]
                                 const float* __restrict__ h_in,     // [B, H]
                                 float* __restrict__ h_out,          // [B, H]
                                 float* __restrict__ c)              // [B, H] in/out
{
  constexpr int BM = 32, BN = 64, BK = 16;
  __shared__ float As[BM][BK + 1];        // +1 pad: kill bank conflicts on column reads
  __shared__ float Bs[4][BK][BN];         // per-gate W tile, k-major
  __shared__ int   ridx[BM];

  const int tid = threadIdx.x;            // 256 threads
  const int tx = tid & 15;                // 16 col-groups
  const int ty = tid >> 4;                // 16 row-groups
  const int m0 = blockIdx.x * BM;
  const int n0 = blockIdx.y * BN;

  if (tid < BM) ridx[tid] = idx_src[(size_t)(m0 + tid) * idx_stride + idx_off];
  __syncthreads();

  float acc[4][2][4];
  #pragma unroll
  for (int g = 0; g < 4; ++g)
    #pragma unroll
    for (int i = 0; i < 2; ++i)
      #pragma unroll
      for (int j = 0; j < 4; ++j) acc[g][i][j] = 0.f;

  const int bcol = tid & 63;              // B-tile loader: col 0..63
  const int bk4  = tid >> 6;              // B-tile loader: k-chunk 0..3

  for (int k0 = 0; k0 < K_TOT; k0 += BK) {
    // ---- stage A tile [32 rows x 16 k] : 128 float4 loads by threads 0..127
    if (tid < 128) {
      int row = tid & 31;
      int k4  = tid >> 5;                 // 0..3
      int kk  = k4 * 4;
      int kg  = k0 + kk;
      float4 v;
      if (kg < E_DIM) v = *(const float4*)(emb + (size_t)ridx[row] * E_DIM + kg);
      else            v = *(const float4*)(h_in + (size_t)(m0 + row) * H_DIM + (kg - E_DIM));
      As[row][kk + 0] = v.x; As[row][kk + 1] = v.y;
      As[row][kk + 2] = v.z; As[row][kk + 3] = v.w;
    }
    // ---- stage B tiles: per gate [16 k x 64 cols], transposed scatter
    {
      int kg = k0 + bk4 * 4;
      #pragma unroll
      for (int g = 0; g < 4; ++g) {
        int j = g * H_DIM + n0 + bcol;    // row of [Wih|Whh]
        float4 v;
        if (kg < E_DIM) v = *(const float4*)(Wih + (size_t)j * E_DIM + kg);
        else            v = *(const float4*)(Whh + (size_t)j * H_DIM + (kg - E_DIM));
        Bs[g][bk4 * 4 + 0][bcol] = v.x; Bs[g][bk4 * 4 + 1][bcol] = v.y;
        Bs[g][bk4 * 4 + 2][bcol] = v.z; Bs[g][bk4 * 4 + 3][bcol] = v.w;
      }
    }
    __syncthreads();
    #pragma unroll
    for (int kk = 0; kk < BK; ++kk) {
      float a[2];
      #pragma unroll
      for (int i = 0; i < 2; ++i) a[i] = As[ty * 2 + i][kk];
      #pragma unroll
      for (int g = 0; g < 4; ++g) {
        float4 bv = *(const float4*)&Bs[g][kk][tx * 4];
        #pragma unroll
        for (int i = 0; i < 2; ++i) {
          acc[g][i][0] = fmaf(a[i], bv.x, acc[g][i][0]);
          acc[g][i][1] = fmaf(a[i], bv.y, acc[g][i][1]);
          acc[g][i][2] = fmaf(a[i], bv.z, acc[g][i][2]);
          acc[g][i][3] = fmaf(a[i], bv.w, acc[g][i][3]);
        }
      }
    }
    __syncthreads();
  }

  // ---- epilogue: bias + LSTM cell update
  const int r0  = m0 + ty * 2;
  const int cn0 = n0 + tx * 4;
  float bsum[4][4];
  #pragma unroll
  for (int g = 0; g < 4; ++g)
    #pragma unroll
    for (int j = 0; j < 4; ++j) {
      int jj = g * H_DIM + cn0 + j;
      bsum[g][j] = bih[jj] + bhh[jj];
    }
  #pragma unroll
  for (int i = 0; i < 2; ++i) {
    int r = r0 + i;
    #pragma unroll
    for (int j = 0; j < 4; ++j) {
      int n = cn0 + j;
      float zi = acc[0][i][j] + bsum[0][j];
      float zf = acc[1][i][j] + bsum[1][j];
      float zg = acc[2][i][j] + bsum[2][j];
      float zo = acc[3][i][j] + bsum[3][j];
      float co = c[(size_t)r * H_DIM + n];
      float cn = sigf(zf) * co + sigf(zi) * tanhf(zg);
      float hn = sigf(zo) * tanhf(cn);
      c[(size_t)r * H_DIM + n]     = cn;
      h_out[(size_t)r * H_DIM + n] = hn;
    }
  }
}

// ---------------------------------------------------------------------------
// logits[b, t, :] = h @ fc_W^T + fc_b   (M=B, N=V=512, K=H=256)
// BM=64, BN=64 -> grid (B/64, V/64) = (32, 8)
// ---------------------------------------------------------------------------
__launch_bounds__(256)
__global__ void logits_kernel(const float* __restrict__ h,    // [B, H]
                              const float* __restrict__ fcW,  // [V, H]
                              const float* __restrict__ fcb,  // [V]
                              float* __restrict__ out,        // [B, T, V]
                              int t, int T)
{
  constexpr int BM = 64, BN = 64, BK = 16;
  __shared__ float As[BM][BK + 1];
  __shared__ float Bs[BK][BN];

  const int tid = threadIdx.x;
  const int tx = tid & 15, ty = tid >> 4;
  const int m0 = blockIdx.x * BM, n0 = blockIdx.y * BN;

  float acc[4][4];
  #pragma unroll
  for (int i = 0; i < 4; ++i)
    #pragma unroll
    for (int j = 0; j < 4; ++j) acc[i][j] = 0.f;

  const int arow = tid & 63, ak4 = tid >> 6;

  for (int k0 = 0; k0 < H_DIM; k0 += BK) {
    {
      int kk = ak4 * 4;
      float4 v = *(const float4*)(h + (size_t)(m0 + arow) * H_DIM + k0 + kk);
      As[arow][kk + 0] = v.x; As[arow][kk + 1] = v.y;
      As[arow][kk + 2] = v.z; As[arow][kk + 3] = v.w;
    }
    {
      float4 v = *(const float4*)(fcW + (size_t)(n0 + arow) * H_DIM + k0 + ak4 * 4);
      Bs[ak4 * 4 + 0][arow] = v.x; Bs[ak4 * 4 + 1][arow] = v.y;
      Bs[ak4 * 4 + 2][arow] = v.z; Bs[ak4 * 4 + 3][arow] = v.w;
    }
    __syncthreads();
    #pragma unroll
    for (int kk = 0; kk < BK; ++kk) {
      float a[4];
      #pragma unroll
      for (int i = 0; i < 4; ++i) a[i] = As[ty * 4 + i][kk];
      float4 bv = *(const float4*)&Bs[kk][tx * 4];
      #pragma unroll
      for (int i = 0; i < 4; ++i) {
        acc[i][0] = fmaf(a[i], bv.x, acc[i][0]);
        acc[i][1] = fmaf(a[i], bv.y, acc[i][1]);
        acc[i][2] = fmaf(a[i], bv.z, acc[i][2]);
        acc[i][3] = fmaf(a[i], bv.w, acc[i][3]);
      }
    }
    __syncthreads();
  }

  #pragma unroll
  for (int j = 0; j < 4; ++j) {
    int v = n0 + tx * 4 + j;
    float bias = fcb[v];
    #pragma unroll
    for (int i = 0; i < 4; ++i) {
      int r = m0 + ty * 4 + i;
      out[(size_t)r * T * V_DIM + (size_t)t * V_DIM + v] = acc[i][j] + bias;
    }
  }
}

// ---------------------------------------------------------------------------
// argmax over V=512 per row; first-index tie-break to match np.argmax.
// One wave (64 lanes) per row.
// ---------------------------------------------------------------------------
__launch_bounds__(256)
__global__ void argmax_kernel(const float* __restrict__ out, int t, int T,
                              int* __restrict__ tok, int B)
{
  const int wave = threadIdx.x >> 6;
  const int lane = threadIdx.x & 63;
  const int row  = blockIdx.x * 4 + wave;
  if (row >= B) return;
  const float* p = out + (size_t)row * T * V_DIM + (size_t)t * V_DIM;
  float best = -INFINITY;
  int   bi   = 0x7fffffff;
  for (int v = lane; v < V_DIM; v += 64) {
    float x = p[v];
    if (x > best) { best = x; bi = v; }   // ascending v: keeps first max in-lane
  }
  #pragma unroll
  for (int off = 32; off; off >>= 1) {
    float ov = __shfl_xor(best, off);
    int   oi = __shfl_xor(bi, off);
    if (ov > best || (ov == best && oi < bi)) { best = ov; bi = oi; }
  }
  if (lane == 0) tok[row] = bi;
}

extern "C" void kernel_launch(void* const* d_in, const int* in_sizes, int n_in,
                              void* d_out, int out_size, void* d_ws, size_t ws_size,
                              hipStream_t stream) {
  const int*   source  = (const int*)d_in[0];
  const float* enc_emb = (const float*)d_in[2];
  const float* enc_Wih = (const float*)d_in[3];
  const float* enc_Whh = (const float*)d_in[4];
  const float* enc_bih = (const float*)d_in[5];
  const float* enc_bhh = (const float*)d_in[6];
  const float* dec_emb = (const float*)d_in[7];
  const float* dec_Wih = (const float*)d_in[8];
  const float* dec_Whh = (const float*)d_in[9];
  const float* dec_bih = (const float*)d_in[10];
  const float* dec_bhh = (const float*)d_in[11];
  const float* fc_W    = (const float*)d_in[12];
  const float* fc_b    = (const float*)d_in[13];
  float* out = (float*)d_out;

  const int B = in_sizes[0] / S_LEN;              // 2048
  const int T = out_size / (B * V_DIM);           // 48

  const size_t BH = (size_t)B * H_DIM;
  float* h0  = (float*)d_ws;
  float* h1  = h0 + BH;
  float* c   = h1 + BH;
  int*   tok = (int*)(c + BH);

  hipMemsetAsync(h0,  0, BH * sizeof(float), stream);
  hipMemsetAsync(c,   0, BH * sizeof(float), stream);
  hipMemsetAsync(tok, 0, (size_t)B * sizeof(int), stream);

  dim3 blk(256);
  dim3 g_gates(B / 32, H_DIM / 64);   // (64, 4) = 256 blocks
  dim3 g_logits(B / 64, V_DIM / 64);  // (32, 8) = 256 blocks
  dim3 g_argmax((B + 3) / 4);

  const float* hin = h0;
  float* hout = h1;

  // ---- encoder ----
  for (int s = 0; s < S_LEN; ++s) {
    lstm_step_kernel<<<g_gates, blk, 0, stream>>>(
        enc_emb, source, S_LEN, s,
        enc_Wih, enc_Whh, enc_bih, enc_bhh, hin, hout, c);
    const float* tmp = hout; hout = (float*)hin; hin = tmp;
  }

  // ---- decoder (greedy, autoregressive) ----
  for (int t = 0; t < T; ++t) {
    lstm_step_kernel<<<g_gates, blk, 0, stream>>>(
        dec_emb, tok, 1, 0,
        dec_Wih, dec_Whh, dec_bih, dec_bhh, hin, hout, c);
    const float* tmp = hout; hout = (float*)hin; hin = tmp;
    logits_kernel<<<g_logits, blk, 0, stream>>>(hin, fc_W, fc_b, out, t, T);
    argmax_kernel<<<g_argmax, blk, 0, stream>>>(out, t, T, tok, B);
  }
}

// Round 2
// 4955.317 us; speedup vs baseline: 1.5960x; 1.5960x over previous
//
#include <hip/hip_runtime.h>
#include <cmath>

#define S_LEN 32
#define E_DIM 128
#define H_DIM 256
#define V_DIM 512

__device__ __forceinline__ float sigf(float x) { return 1.0f / (1.0f + expf(-x)); }

// ---------------------------------------------------------------------------
// Fused LSTM step: Z = [emb[idx] | h_in] @ [Wih | Whh]^T + bih + bhh,
// then i,f,g,o cell update.
// Block: BM=64 rows x (4 gates x BN=32 hidden cols). Grid (B/64, H/32) = (32,8).
// Per thread: 4 rows x 4 gates x 2 cols, BK=32.
// LDS demand in inner loop: 12 words / 32 FMA = 0.75 B/FLOP (vs 1.125 in v1).
// ---------------------------------------------------------------------------
__launch_bounds__(256)
__global__ void lstm_step_kernel(const float* __restrict__ emb,      // [V, E]
                                 const int* __restrict__ idx_src,
                                 int idx_stride, int idx_off,
                                 const float* __restrict__ Wih,      // [4H, E]
                                 const float* __restrict__ Whh,      // [4H, H]
                                 const float* __restrict__ bih,      // [4H]
                                 const float* __restrict__ bhh,      // [4H]
                                 const float* __restrict__ h_in,     // [B, H]
                                 float* __restrict__ h_out,          // [B, H]
                                 float* __restrict__ c)              // [B, H] in/out
{
  __shared__ float As[64][36];          // 36-float row stride: 144 B = 9*16, f4-aligned
  __shared__ float Bs[4][32][32];       // [gate][k][col]
  __shared__ int   ridx[64];

  const int tid = threadIdx.x;          // 256
  const int tx  = tid & 15;             // 16 col-groups (2 cols each)
  const int ty  = tid >> 4;             // 16 row-groups (4 rows each)
  const int m0  = blockIdx.x * 64;
  const int n0  = blockIdx.y * 32;

  if (tid < 64) ridx[tid] = idx_src[(size_t)(m0 + tid) * idx_stride + idx_off];
  __syncthreads();

  float acc[4][4][2] = {};              // [gate][row][col]

  // A-stage mapping: 512 float4 per tile, 2 per thread
  const int arow = tid >> 2;            // 0..63
  const int aq   = tid & 3;             // 0..3
  // B-stage mapping: thread loads 16 consecutive k-floats of one W row
  const int bg   = tid >> 6;            // gate 0..3
  const int bc   = tid & 31;            // col 0..31
  const int bh   = (tid >> 5) & 1;      // k-half 0/1
  const int brow = bg * H_DIM + n0 + bc;

  for (int k0 = 0; k0 < E_DIM + H_DIM; k0 += 32) {
    // ---- stage A [64 x 32]
    {
      const float* src;
      if (k0 < E_DIM) src = emb  + (size_t)ridx[arow] * E_DIM + k0;
      else            src = h_in + (size_t)(m0 + arow) * H_DIM + (k0 - E_DIM);
      float4 v0 = *(const float4*)(src + aq * 4);
      float4 v1 = *(const float4*)(src + aq * 4 + 16);
      *(float4*)&As[arow][aq * 4]      = v0;
      *(float4*)&As[arow][aq * 4 + 16] = v1;
    }
    // ---- stage B [4][32 k][32 col] (transposed scatter)
    {
      const float* src;
      if (k0 < E_DIM) src = Wih + (size_t)brow * E_DIM + k0 + bh * 16;
      else            src = Whh + (size_t)brow * H_DIM + (k0 - E_DIM) + bh * 16;
      float4 w0 = *(const float4*)(src + 0);
      float4 w1 = *(const float4*)(src + 4);
      float4 w2 = *(const float4*)(src + 8);
      float4 w3 = *(const float4*)(src + 12);
      float w[16] = {w0.x, w0.y, w0.z, w0.w, w1.x, w1.y, w1.z, w1.w,
                     w2.x, w2.y, w2.z, w2.w, w3.x, w3.y, w3.z, w3.w};
      #pragma unroll
      for (int q = 0; q < 16; ++q) Bs[bg][bh * 16 + q][bc] = w[q];
    }
    __syncthreads();

    #pragma unroll
    for (int kk = 0; kk < 32; ++kk) {
      float a0 = As[ty * 4 + 0][kk];
      float a1 = As[ty * 4 + 1][kk];
      float a2 = As[ty * 4 + 2][kk];
      float a3 = As[ty * 4 + 3][kk];
      #pragma unroll
      for (int g = 0; g < 4; ++g) {
        float b0 = Bs[g][kk][tx * 2 + 0];
        float b1 = Bs[g][kk][tx * 2 + 1];
        acc[g][0][0] = fmaf(a0, b0, acc[g][0][0]);
        acc[g][0][1] = fmaf(a0, b1, acc[g][0][1]);
        acc[g][1][0] = fmaf(a1, b0, acc[g][1][0]);
        acc[g][1][1] = fmaf(a1, b1, acc[g][1][1]);
        acc[g][2][0] = fmaf(a2, b0, acc[g][2][0]);
        acc[g][2][1] = fmaf(a2, b1, acc[g][2][1]);
        acc[g][3][0] = fmaf(a3, b0, acc[g][3][0]);
        acc[g][3][1] = fmaf(a3, b1, acc[g][3][1]);
      }
    }
    __syncthreads();
  }

  // ---- epilogue: bias + cell update (float2 per row)
  const int r0  = m0 + ty * 4;
  const int cn0 = n0 + tx * 2;
  float bsum[4][2];
  #pragma unroll
  for (int g = 0; g < 4; ++g)
    #pragma unroll
    for (int j = 0; j < 2; ++j) {
      int jj = g * H_DIM + cn0 + j;
      bsum[g][j] = bih[jj] + bhh[jj];
    }
  #pragma unroll
  for (int i = 0; i < 4; ++i) {
    int r = r0 + i;
    float2 co = *(const float2*)(c + (size_t)r * H_DIM + cn0);
    float2 cn, hn;
    {
      float zi = acc[0][i][0] + bsum[0][0];
      float zf = acc[1][i][0] + bsum[1][0];
      float zg = acc[2][i][0] + bsum[2][0];
      float zo = acc[3][i][0] + bsum[3][0];
      cn.x = sigf(zf) * co.x + sigf(zi) * tanhf(zg);
      hn.x = sigf(zo) * tanhf(cn.x);
    }
    {
      float zi = acc[0][i][1] + bsum[0][1];
      float zf = acc[1][i][1] + bsum[1][1];
      float zg = acc[2][i][1] + bsum[2][1];
      float zo = acc[3][i][1] + bsum[3][1];
      cn.y = sigf(zf) * co.y + sigf(zi) * tanhf(zg);
      hn.y = sigf(zo) * tanhf(cn.y);
    }
    *(float2*)(c     + (size_t)r * H_DIM + cn0) = cn;
    *(float2*)(h_out + (size_t)r * H_DIM + cn0) = hn;
  }
}

// ---------------------------------------------------------------------------
// Fused logits + argmax: logits[b,t,:] = h @ fcW^T + fcb; tok[b] = argmax.
// Block owns 8 rows x all 512 cols. Grid = B/8 = 256. Wave w owns rows 2w,2w+1;
// lane owns cols {lane + 64*i}. First-index tie-break matches np.argmax.
// ---------------------------------------------------------------------------
__launch_bounds__(256)
__global__ void declog_kernel(const float* __restrict__ h,    // [B, H]
                              const float* __restrict__ fcW,  // [V, H]
                              const float* __restrict__ fcb,  // [V]
                              float* __restrict__ out,        // [B, T, V]
                              int* __restrict__ tok,          // [B]
                              int t, int T)
{
  __shared__ float As[8][264];          // 264 floats = 1056 B row stride, f4-aligned
  __shared__ float Bs[16][V_DIM];       // 32 KB

  const int tid  = threadIdx.x;
  const int lane = tid & 63;
  const int wv   = tid >> 6;            // wave 0..3
  const int r0   = blockIdx.x * 8;

  // ---- stage A: 8 rows x 256 = 512 float4, 2 per thread, coalesced
  #pragma unroll
  for (int s = 0; s < 2; ++s) {
    int f4 = s * 256 + tid;
    int row = f4 >> 6, q = f4 & 63;
    float4 v = *(const float4*)(h + (size_t)(r0 + row) * H_DIM + q * 4);
    *(float4*)&As[row][q * 4] = v;
  }

  float acc[2][8] = {};
  const int v0 = tid * 2;               // this thread stages fcW rows v0, v0+1

  for (int k0 = 0; k0 < H_DIM; k0 += 16) {
    __syncthreads();
    #pragma unroll
    for (int s = 0; s < 2; ++s) {
      const float* src = fcW + (size_t)(v0 + s) * H_DIM + k0;
      float4 w0 = *(const float4*)(src + 0);
      float4 w1 = *(const float4*)(src + 4);
      float4 w2 = *(const float4*)(src + 8);
      float4 w3 = *(const float4*)(src + 12);
      float w[16] = {w0.x, w0.y, w0.z, w0.w, w1.x, w1.y, w1.z, w1.w,
                     w2.x, w2.y, w2.z, w2.w, w3.x, w3.y, w3.z, w3.w};
      #pragma unroll
      for (int q = 0; q < 16; ++q) Bs[q][v0 + s] = w[q];
    }
    __syncthreads();

    #pragma unroll
    for (int kk = 0; kk < 16; ++kk) {
      float a0 = As[wv * 2 + 0][k0 + kk];
      float a1 = As[wv * 2 + 1][k0 + kk];
      #pragma unroll
      for (int i = 0; i < 8; ++i) {
        float b = Bs[kk][lane + 64 * i];
        acc[0][i] = fmaf(a0, b, acc[0][i]);
        acc[1][i] = fmaf(a1, b, acc[1][i]);
      }
    }
  }

  // ---- bias, store logits, argmax
  float bias[8];
  #pragma unroll
  for (int i = 0; i < 8; ++i) bias[i] = fcb[lane + 64 * i];

  #pragma unroll
  for (int r = 0; r < 2; ++r) {
    int row = r0 + wv * 2 + r;
    float* op = out + (size_t)row * T * V_DIM + (size_t)t * V_DIM;
    float best = -INFINITY;
    int   bi   = 0x7fffffff;
    #pragma unroll
    for (int i = 0; i < 8; ++i) {
      float x = acc[r][i] + bias[i];
      op[lane + 64 * i] = x;
      if (x > best) { best = x; bi = lane + 64 * i; }  // i ascending => first max kept
    }
    #pragma unroll
    for (int off = 32; off; off >>= 1) {
      float ov = __shfl_xor(best, off);
      int   oi = __shfl_xor(bi, off);
      if (ov > best || (ov == best && oi < bi)) { best = ov; bi = oi; }
    }
    if (lane == 0) tok[row] = bi;
  }
}

extern "C" void kernel_launch(void* const* d_in, const int* in_sizes, int n_in,
                              void* d_out, int out_size, void* d_ws, size_t ws_size,
                              hipStream_t stream) {
  const int*   source  = (const int*)d_in[0];
  const float* enc_emb = (const float*)d_in[2];
  const float* enc_Wih = (const float*)d_in[3];
  const float* enc_Whh = (const float*)d_in[4];
  const float* enc_bih = (const float*)d_in[5];
  const float* enc_bhh = (const float*)d_in[6];
  const float* dec_emb = (const float*)d_in[7];
  const float* dec_Wih = (const float*)d_in[8];
  const float* dec_Whh = (const float*)d_in[9];
  const float* dec_bih = (const float*)d_in[10];
  const float* dec_bhh = (const float*)d_in[11];
  const float* fc_W    = (const float*)d_in[12];
  const float* fc_b    = (const float*)d_in[13];
  float* out = (float*)d_out;

  const int B = in_sizes[0] / S_LEN;              // 2048
  const int T = out_size / (B * V_DIM);           // 48

  const size_t BH = (size_t)B * H_DIM;
  float* h0  = (float*)d_ws;
  float* h1  = h0 + BH;
  float* c   = h1 + BH;
  int*   tok = (int*)(c + BH);

  hipMemsetAsync(h0,  0, BH * sizeof(float), stream);
  hipMemsetAsync(c,   0, BH * sizeof(float), stream);
  hipMemsetAsync(tok, 0, (size_t)B * sizeof(int), stream);

  dim3 blk(256);
  dim3 g_lstm(B / 64, H_DIM / 32);    // (32, 8) = 256 blocks
  dim3 g_declog(B / 8);               // 256 blocks

  const float* hin = h0;
  float* hout = h1;

  // ---- encoder ----
  for (int s = 0; s < S_LEN; ++s) {
    lstm_step_kernel<<<g_lstm, blk, 0, stream>>>(
        enc_emb, source, S_LEN, s,
        enc_Wih, enc_Whh, enc_bih, enc_bhh, hin, hout, c);
    const float* tmp = hout; hout = (float*)hin; hin = tmp;
  }

  // ---- decoder (greedy, autoregressive) ----
  for (int t = 0; t < T; ++t) {
    lstm_step_kernel<<<g_lstm, blk, 0, stream>>>(
        dec_emb, tok, 1, 0,
        dec_Wih, dec_Whh, dec_bih, dec_bhh, hin, hout, c);
    const float* tmp = hout; hout = (float*)hin; hin = tmp;
    declog_kernel<<<g_declog, blk, 0, stream>>>(hin, fc_W, fc_b, out, tok, t, T);
  }
}